// Round 5
// baseline (225.033 us; speedup 1.0000x reference)
//
#include <hip/hip_runtime.h>
#include <stdint.h>

namespace {
constexpr int BATCH  = 512;
constexpr int CBS    = 320;       // combined batch size
constexpr int R      = 64;        // rank
constexpr int K      = 4096;
constexpr int NADAPT = 80;
constexpr int GRP    = 4;         // combos per block (always wid-uniform)
constexpr int NGMAX  = 140;       // max groups: sum ceil(cnt/4) <= (320+3*80)/4
constexpr int SPLIT  = 8;         // k-slices
constexpr int KS     = K / SPLIT; // 512 k per block
constexpr int TK     = 32;        // k per LDS tile
constexpr int NTILE  = KS / TK;   // 16
constexpr int NT     = 256;       // 4 waves

// ws layout: hdr[16] ints at 0 (hdr[0]=ng); grp[NGMAX*4] ints at byte 64;
// x_bf16[512][4096] at byte 4096
constexpr size_t WS_GRP_OFF = 64;
constexpr size_t WS_X_OFF   = 4096;
constexpr size_t WS_NEEDED  = WS_X_OFF + (size_t)BATCH * K * 2;  // ~4.2 MiB

__device__ inline uint16_t f2bf(float f) {   // RNE fp32 -> bf16
    uint32_t u = __float_as_uint(f);
    u += 0x7fffu + ((u >> 16) & 1u);
    return (uint16_t)(u >> 16);
}
__device__ inline float bflo(uint32_t u) { return __uint_as_float(u << 16); }
__device__ inline float bfhi(uint32_t u) { return __uint_as_float(u & 0xffff0000u); }

__device__ __forceinline__ void dot8(float& acc, const uint4 v, const float (&a)[8]) {
    acc = fmaf(bflo(v.x), a[0], acc);
    acc = fmaf(bfhi(v.x), a[1], acc);
    acc = fmaf(bflo(v.y), a[2], acc);
    acc = fmaf(bfhi(v.y), a[3], acc);
    acc = fmaf(bflo(v.z), a[4], acc);
    acc = fmaf(bfhi(v.z), a[5], acc);
    acc = fmaf(bflo(v.w), a[6], acc);
    acc = fmaf(bfhi(v.w), a[7], acc);
}

#define WAITL() asm volatile("s_waitcnt lgkmcnt(0)" ::: "memory")
#define SCHED0() __builtin_amdgcn_sched_barrier(0)
#define SBAR()  __builtin_amdgcn_s_barrier()

// One pipelined 32-k tile. Steady-state invariant entering tile T: 12
// outstanding vmem = x(T+1) 4 loads + A(T) 8 loads. Issue the next 12, then
// vmcnt(WN) retires exactly the previous 12 (FIFO), leaving 12 in flight
// ACROSS the raw barrier.
//
// LDS geometry (16B slots): SLOT(c,r,j) = c*256 + r*4 + (j ^ ((r>>1)&3)).
//  - write instr: lane l covers row 16i+(l>>2), quad j=l&3 -> slots are 64
//    consecutive 16B (permuted in 4-groups): conflict-free.
//  - read instr (fixed c, j=wv): slot%8 spans all 8 bank-quads per 8 lanes.
template<int T, bool IX2, bool IA1, bool WRT, int WN>
__device__ __forceinline__ void body(
    uint4* __restrict__ xsb,                  // &xs[0][0] : [2][1024] 16B slots
    const uint16_t* const (&xp)[4],           // lane's 4 pre-offset row pointers
    const float* __restrict__ Ab,
    int wv, int rdi, int swi,
    uint4 (&pxN)[4], const uint4 (&pxW)[4],
    float (&aN)[8], const float (&aC)[8],
    float& acc0, float& acc1, float& acc2, float& acc3)
{
    const uint4* Bp = xsb + (T & 1) * 1024 + rdi;
    const uint4 xv0 = Bp[0];
    const uint4 xv1 = Bp[256];
    const uint4 xv2 = Bp[512];
    const uint4 xv3 = Bp[768];
    if constexpr (IX2) {                      // issue x(T+2): 4 x dwordx4
#pragma unroll
        for (int i = 0; i < 4; ++i)
            pxN[i] = *(const uint4*)(xp[i] + (T + 2) * TK);
    }
    if constexpr (IA1) {                      // issue A(T+1): 8 coalesced dwords
#pragma unroll
        for (int q = 0; q < 8; ++q)
            aN[q] = Ab[((size_t)((T + 1) * TK) + wv * 8 + q) * R];
    }
    asm volatile("s_waitcnt vmcnt(%0)" :: "i"(WN) : "memory"); // x(T+1),A(T) landed
    WAITL();                                   // ds_reads landed
    SCHED0();
    dot8(acc0, xv0, aC);
    dot8(acc1, xv1, aC);
    dot8(acc2, xv2, aC);
    dot8(acc3, xv3, aC);
    if constexpr (WRT) {                       // write x(T+1) into other buffer
        uint4* wb = xsb + ((T + 1) & 1) * 1024 + swi;
#pragma unroll
        for (int i = 0; i < 4; ++i)
            wb[64 * i] = pxW[i];
        WAITL(); SCHED0();
        SBAR();                                // raw barrier: no vmcnt drain
        SCHED0();
    }
}
}

// ---- pre-pass (fused): block 0 = wid-sort + per-adapter group build;
//      blocks 1..2048 = x fp32->bf16; trailing blocks zero `out` ----
__global__ __launch_bounds__(256)
void prep(const float* __restrict__ x, uint16_t* __restrict__ xb,
          const int* __restrict__ wids, int* __restrict__ hdr,
          int* __restrict__ grp, float* __restrict__ out, int out_size)
{
    const int bid = blockIdx.x;
    const int t   = threadIdx.x;
    if (bid == 0) {
        __shared__ int hist[NADAPT];
        __shared__ int offs[NADAPT];
        __shared__ int gbase[NADAPT + 1];
        __shared__ int sperm[CBS];
        if (t < NADAPT) hist[t] = 0;
        __syncthreads();
        for (int c = t; c < CBS; c += 256) atomicAdd(&hist[wids[c]], 1);
        __syncthreads();
        if (t == 0) {
            int run = 0, grun = 0;
            for (int i = 0; i < NADAPT; ++i) {
                offs[i]  = run;  run  += hist[i];
                gbase[i] = grun; grun += (hist[i] + GRP - 1) / GRP;
            }
            gbase[NADAPT] = grun;
            hdr[0] = grun;                 // ng
        }
        __syncthreads();
        for (int c = t; c < CBS; c += 256) {
            const int pos = atomicAdd(&offs[wids[c]], 1);
            sperm[pos] = c;
        }
        __syncthreads();
        for (int w = t; w < NADAPT; w += 256) {   // emit uniform groups (pad -1)
            const int cnt   = hist[w];
            const int start = offs[w] - cnt;
            const int gb    = gbase[w];
            for (int i = 0; i < cnt; i += GRP) {
                const int gi = gb + i / GRP;
#pragma unroll
                for (int j = 0; j < GRP; ++j)
                    grp[GRP * gi + j] = (i + j < cnt) ? sperm[start + i + j] : -1;
            }
        }
    } else if (bid <= BATCH * K / 1024) {          // 2048 cvt blocks
        const int i = (bid - 1) * 256 + t;
        const float4 v = ((const float4*)x)[i];
        ushort4 o;
        o.x = f2bf(v.x); o.y = f2bf(v.y); o.z = f2bf(v.z); o.w = f2bf(v.w);
        ((ushort4*)xb)[i] = o;
    } else {                                       // zero out[]
        const int i4 = (bid - (1 + BATCH * K / 1024)) * 256 + t;
        const int e  = i4 * 4;
        if (e + 3 < out_size) {
            ((float4*)out)[i4] = make_float4(0.f, 0.f, 0.f, 0.f);
        } else {
            for (int q = e; q < out_size; ++q) out[q] = 0.f;
        }
    }
}

// ---- main: block (g, s) = one wid-uniform group (<=4 combos) x 512-k slice.
// Gather re-shaped for probe economy: staging instr = 16 rows x 4 lanes x 16B
// -> one aligned 64B line-probe per row (4x fewer probes than lane-per-row).
// Counted-vmcnt pipeline (12 outstanding steady), raw barriers, A shared
// in-register across the 4 combos. No shuffles; lane-local k-reduction.
__global__ __launch_bounds__(NT, 4)
void lora_main(const int* __restrict__ xids,
               const int* __restrict__ wids,
               const float* __restrict__ A,
               const uint16_t* __restrict__ xb,
               const int* __restrict__ hdr,
               const int* __restrict__ grp,
               float* __restrict__ out)
{
    __shared__ __align__(16) uint4 xs[2][1024];   // 2 x 16 KiB (double-buffered)
    __shared__ float red[4 * GRP * 64];           // 4 KiB

    const int bid = blockIdx.x;
    const int g   = bid >> 3;
    const int s   = bid & 7;
    if (g >= hdr[0]) return;                // inactive tail blocks

    const int t  = threadIdx.x;
    const int wv = t >> 6;
    const int r  = t & 63;

    const int* gp = grp + GRP * g;
    const int gc0 = gp[0], gc1 = gp[1], gc2 = gp[2], gc3 = gp[3];
    const int myc_raw = (wv == 0) ? gc0 : (wv == 1) ? gc1 : (wv == 2) ? gc2 : gc3;
    const int myc = (myc_raw >= 0) ? myc_raw : gc0;   // pad slots stage dup x
    const int wid = wids[gc0];                        // group is wid-uniform

    // staging: wave wv = combo wv; instr i covers rows 16i+(r>>2), lane window
    // (r&3)*16B of the row's 64B tile-chunk
    const uint16_t* xp[4];
#pragma unroll
    for (int i = 0; i < 4; ++i)
        xp[i] = xb + (size_t)xids[myc * R + 16 * i + (r >> 2)] * K
                   + s * KS + (r & 3) * 8;

    // LDS index bases (16B slots)
    const int rdi = r * 4 + (wv ^ ((r >> 1) & 3));                  // read
    const int swi = wv * 256 + (r >> 2) * 4 + ((r & 3) ^ ((r >> 3) & 3)); // write

    const float* __restrict__ Ab =
        A + (size_t)wid * (K * R) + (size_t)(s * KS) * R + r;

    float acc0 = 0.f, acc1 = 0.f, acc2 = 0.f, acc3 = 0.f;
    uint4 pxA[4], pxB[4];
    float aA[8], aB[8];

    // ---- prologue: x(0)->pxA, x(1)->pxB, A(0)->aA ----
    {
#pragma unroll
        for (int i = 0; i < 4; ++i) pxA[i] = *(const uint4*)(xp[i]);
        SCHED0();
#pragma unroll
        for (int i = 0; i < 4; ++i) pxB[i] = *(const uint4*)(xp[i] + TK);
        SCHED0();
#pragma unroll
        for (int q = 0; q < 8; ++q) aA[q] = Ab[(size_t)(wv * 8 + q) * R];
        asm volatile("s_waitcnt vmcnt(12)" ::: "memory");   // x(0) landed
        uint4* wb = &xs[0][0] + swi;
#pragma unroll
        for (int i = 0; i < 4; ++i) wb[64 * i] = pxA[i];
        WAITL(); SCHED0();
        SBAR();
        SCHED0();
    }
    // entering loop: 12 outstanding = x(1) 4 + A(0) 8

    uint4* xsb = &xs[0][0];
    body< 0, true,  true,  true, 12>(xsb, xp, Ab, wv, rdi, swi, pxA, pxB, aB, aA, acc0, acc1, acc2, acc3);
    body< 1, true,  true,  true, 12>(xsb, xp, Ab, wv, rdi, swi, pxB, pxA, aA, aB, acc0, acc1, acc2, acc3);
    body< 2, true,  true,  true, 12>(xsb, xp, Ab, wv, rdi, swi, pxA, pxB, aB, aA, acc0, acc1, acc2, acc3);
    body< 3, true,  true,  true, 12>(xsb, xp, Ab, wv, rdi, swi, pxB, pxA, aA, aB, acc0, acc1, acc2, acc3);
    body< 4, true,  true,  true, 12>(xsb, xp, Ab, wv, rdi, swi, pxA, pxB, aB, aA, acc0, acc1, acc2, acc3);
    body< 5, true,  true,  true, 12>(xsb, xp, Ab, wv, rdi, swi, pxB, pxA, aA, aB, acc0, acc1, acc2, acc3);
    body< 6, true,  true,  true, 12>(xsb, xp, Ab, wv, rdi, swi, pxA, pxB, aB, aA, acc0, acc1, acc2, acc3);
    body< 7, true,  true,  true, 12>(xsb, xp, Ab, wv, rdi, swi, pxB, pxA, aA, aB, acc0, acc1, acc2, acc3);
    body< 8, true,  true,  true, 12>(xsb, xp, Ab, wv, rdi, swi, pxA, pxB, aB, aA, acc0, acc1, acc2, acc3);
    body< 9, true,  true,  true, 12>(xsb, xp, Ab, wv, rdi, swi, pxB, pxA, aA, aB, acc0, acc1, acc2, acc3);
    body<10, true,  true,  true, 12>(xsb, xp, Ab, wv, rdi, swi, pxA, pxB, aB, aA, acc0, acc1, acc2, acc3);
    body<11, true,  true,  true, 12>(xsb, xp, Ab, wv, rdi, swi, pxB, pxA, aA, aB, acc0, acc1, acc2, acc3);
    body<12, true,  true,  true, 12>(xsb, xp, Ab, wv, rdi, swi, pxA, pxB, aB, aA, acc0, acc1, acc2, acc3);
    body<13, true,  true,  true, 12>(xsb, xp, Ab, wv, rdi, swi, pxB, pxA, aA, aB, acc0, acc1, acc2, acc3);
    body<14, false, true,  true,  8>(xsb, xp, Ab, wv, rdi, swi, pxA, pxB, aB, aA, acc0, acc1, acc2, acc3);
    body<15, false, false, false, 0>(xsb, xp, Ab, wv, rdi, swi, pxB, pxA, aA, aB, acc0, acc1, acc2, acc3);

    // ---- cross-wave reduce: red[srcwave][slot][r]; wave wv finalizes slot wv ----
    red[wv * 256 +   0 + r] = acc0;
    red[wv * 256 +  64 + r] = acc1;
    red[wv * 256 + 128 + r] = acc2;
    red[wv * 256 + 192 + r] = acc3;
    __syncthreads();
    const float sum = red[0 * 256 + wv * 64 + r] + red[1 * 256 + wv * 64 + r] +
                      red[2 * 256 + wv * 64 + r] + red[3 * 256 + wv * 64 + r];
    if (myc_raw >= 0)
        atomicAdd(&out[myc_raw * R + r], sum);
}

// ---- fallback (ws too small): fp32 x from global, LDS transpose, no perm ----
__global__ __launch_bounds__(NT)
void lora_fallback(const float* __restrict__ x,
                   const int*   __restrict__ xids,
                   const int*   __restrict__ wids,
                   const float* __restrict__ A,
                   float*       __restrict__ out)
{
    constexpr int FKS = 512, FTK = 64, FNT_TILES = 8, FNW = 4;
    __shared__ float xsf[FTK * R];
    __shared__ float red[FNW * R];
    const int bid  = blockIdx.x;
    const int c    = bid >> 3;
    const int s    = bid & 7;
    const int t    = threadIdx.x;
    const int wave = t >> 6;
    const int lane = t & 63;
    const int r4   = lane & 15;
    const int kq   = lane >> 4;
    const int wid  = wids[c];
    const float* __restrict__ Aw = A + (size_t)wid * (K * R);
    const int rw  = t >> 2;
    const int jq  = t & 3;
    const int tok = xids[c * R + rw];
    const float* __restrict__ xrow = x + (size_t)tok * K + s * FKS + jq * 16;
    float4 acc = make_float4(0.f, 0.f, 0.f, 0.f);
    float4 pv[4];
    {
        const float4* src = (const float4*)xrow;
#pragma unroll
        for (int ii = 0; ii < 4; ++ii) pv[ii] = src[ii];
    }
    for (int tile = 0; tile < FNT_TILES; ++tile) {
#pragma unroll
        for (int ii = 0; ii < 4; ++ii) {
            const int kk = jq * 16 + ii * 4;
            xsf[(kk + 0) * R + rw] = pv[ii].x;
            xsf[(kk + 1) * R + rw] = pv[ii].y;
            xsf[(kk + 2) * R + rw] = pv[ii].z;
            xsf[(kk + 3) * R + rw] = pv[ii].w;
        }
        __syncthreads();
        if (tile + 1 < FNT_TILES) {
            const float4* src = (const float4*)(xrow + (tile + 1) * FTK);
#pragma unroll
            for (int ii = 0; ii < 4; ++ii) pv[ii] = src[ii];
        }
        const int kw = wave * 16 + kq;
        const float* __restrict__ Ap =
            Aw + (size_t)(s * FKS + tile * FTK + kw) * R + 4 * r4;
#pragma unroll
        for (int i = 0; i < 4; ++i) {
            float4 av = *(const float4*)(Ap + (size_t)(4 * i) * R);
            float4 xv = *(const float4*)(&xsf[(kw + 4 * i) * R + 4 * r4]);
            acc.x = fmaf(xv.x, av.x, acc.x);
            acc.y = fmaf(xv.y, av.y, acc.y);
            acc.z = fmaf(xv.z, av.z, acc.z);
            acc.w = fmaf(xv.w, av.w, acc.w);
        }
        __syncthreads();
    }
#pragma unroll
    for (int m = 16; m < 64; m <<= 1) {
        acc.x += __shfl_xor(acc.x, m, 64);
        acc.y += __shfl_xor(acc.y, m, 64);
        acc.z += __shfl_xor(acc.z, m, 64);
        acc.w += __shfl_xor(acc.w, m, 64);
    }
    if (kq == 0) {
        float* rd = &red[wave * R + 4 * r4];
        rd[0] = acc.x; rd[1] = acc.y; rd[2] = acc.z; rd[3] = acc.w;
    }
    __syncthreads();
    if (wave == 0) {
        float sum = red[lane] + red[R + lane] + red[2 * R + lane] + red[3 * R + lane];
        atomicAdd(&out[c * R + lane], sum);
    }
}

extern "C" void kernel_launch(void* const* d_in, const int* in_sizes, int n_in,
                              void* d_out, int out_size, void* d_ws, size_t ws_size,
                              hipStream_t stream)
{
    (void)in_sizes; (void)n_in;
    const float* x    = (const float*)d_in[0];
    const int*   xids = (const int*)d_in[1];
    const int*   wids = (const int*)d_in[2];
    const float* A    = (const float*)d_in[3];
    float* out        = (float*)d_out;

    if (ws_size >= WS_NEEDED) {
        int*      hdr = (int*)d_ws;
        int*      grp = (int*)((char*)d_ws + WS_GRP_OFF);
        uint16_t* xbw = (uint16_t*)((char*)d_ws + WS_X_OFF);
        const int ncvt = BATCH * K / 1024;              // 2048
        const int nz   = (out_size + 1023) / 1024;      // out-zero blocks
        hipLaunchKernelGGL(prep, dim3(1 + ncvt + nz), dim3(256), 0, stream,
                           x, xbw, wids, hdr, grp, out, out_size);
        hipLaunchKernelGGL(lora_main, dim3(NGMAX * SPLIT), dim3(NT), 0, stream,
                           xids, wids, A, xbw, hdr, grp, out);
    } else {
        hipMemsetAsync(out, 0, (size_t)out_size * sizeof(float), stream);
        hipLaunchKernelGGL(lora_fallback, dim3(CBS * 8), dim3(NT), 0, stream,
                           x, xids, wids, A, out);
    }
}

// Round 6
// 151.356 us; speedup vs baseline: 1.4868x; 1.4868x over previous
//
#include <hip/hip_runtime.h>
#include <stdint.h>

namespace {
constexpr int BATCH  = 512;
constexpr int CBS    = 320;       // combined batch size
constexpr int R      = 64;        // rank
constexpr int K      = 4096;
constexpr int NADAPT = 80;
constexpr int GRP    = 4;         // combos per block (always wid-uniform)
constexpr int NGMAX  = 140;       // max groups: sum ceil(cnt/4) <= (320+3*80)/4
constexpr int SPLIT  = 8;         // k-slices
constexpr int KS     = K / SPLIT; // 512 k per block
constexpr int TK     = 32;        // k per LDS tile (64 B per row)
constexpr int NTILE  = KS / TK;   // 16
constexpr int NT     = 256;       // 4 waves

// ws layout: hdr[16] ints at 0 (hdr[0]=ng); grp[NGMAX*4] ints at byte 64;
// x_bf16[512][4096] at byte 4096
constexpr size_t WS_GRP_OFF = 64;
constexpr size_t WS_X_OFF   = 4096;
constexpr size_t WS_NEEDED  = WS_X_OFF + (size_t)BATCH * K * 2;  // ~4.2 MiB

__device__ inline uint16_t f2bf(float f) {   // RNE fp32 -> bf16
    uint32_t u = __float_as_uint(f);
    u += 0x7fffu + ((u >> 16) & 1u);
    return (uint16_t)(u >> 16);
}
__device__ inline float bflo(uint32_t u) { return __uint_as_float(u << 16); }
__device__ inline float bfhi(uint32_t u) { return __uint_as_float(u & 0xffff0000u); }

__device__ __forceinline__ void dot8(float& acc, const uint4 v, const float (&a)[8]) {
    acc = fmaf(bflo(v.x), a[0], acc);
    acc = fmaf(bfhi(v.x), a[1], acc);
    acc = fmaf(bflo(v.y), a[2], acc);
    acc = fmaf(bfhi(v.y), a[3], acc);
    acc = fmaf(bflo(v.z), a[4], acc);
    acc = fmaf(bfhi(v.z), a[5], acc);
    acc = fmaf(bflo(v.w), a[6], acc);
    acc = fmaf(bfhi(v.w), a[7], acc);
}

#define WAITL() asm volatile("s_waitcnt lgkmcnt(0)" ::: "memory")
#define SCHED0() __builtin_amdgcn_sched_barrier(0)
#define SBAR()  __builtin_amdgcn_s_barrier()

// DMA 16 B/lane global->LDS. LDS dest = wave-uniform base + lane*16 (linear);
// the swizzle lives in the per-lane GLOBAL address (rule #21: pre-swizzled
// source + swizzled read, LDS stays linear).
__device__ __forceinline__ void gload_lds16(const void* g, void* l) {
    __builtin_amdgcn_global_load_lds(
        (const __attribute__((address_space(1))) void*)g,
        (__attribute__((address_space(3))) void*)l, 16, 0, 0);
}

// One pipelined 32-k tile. Entering tile T (post-barrier): outstanding = A(T):8.
// Issue x(T+1) 4 DMAs + A(T+1) 8 loads -> 20 outstanding; vmcnt(12) retires
// A(T) for the FMAs; vmcnt(8) retires x(T+1) before the barrier. Never 0
// in-loop (T3/T4).
template<int T, bool NOTLAST>
__device__ __forceinline__ void body(
    uint4* __restrict__ xsb,                  // &xs[0][0] : [2][1024] 16B slots
    const char* __restrict__ xbase,           // xb + s*KS*2 + jq*16 (lane-swizzled)
    const uint32_t (&tokoff)[4],              // per-instr token-row byte offsets
    const float* __restrict__ Ab,
    int wv, int rdi,
    float (&aN)[8], const float (&aC)[8],
    float& acc0, float& acc1, float& acc2, float& acc3)
{
    if constexpr (NOTLAST) {                  // issue x(T+1) -> other buffer
        uint4* ldst = xsb + ((T + 1) & 1) * 1024 + wv * 256;
#pragma unroll
        for (int i = 0; i < 4; ++i)
            gload_lds16(xbase + tokoff[i] + (size_t)(T + 1) * 64,
                        (void*)(ldst + i * 64));
    }
    const uint4* Bp = xsb + (T & 1) * 1024 + rdi;
    const uint4 xv0 = Bp[0];
    const uint4 xv1 = Bp[256];
    const uint4 xv2 = Bp[512];
    const uint4 xv3 = Bp[768];
    if constexpr (NOTLAST) {                  // issue A(T+1): 8 coalesced dwords
#pragma unroll
        for (int q = 0; q < 8; ++q)
            aN[q] = Ab[((size_t)((T + 1) * TK) + wv * 8 + q) * R];
    }
    if constexpr (NOTLAST) {
        asm volatile("s_waitcnt vmcnt(12)" ::: "memory");  // A(T) landed
    } else {
        asm volatile("s_waitcnt vmcnt(0)" ::: "memory");   // epilogue drain
    }
    WAITL();                                   // ds_reads landed
    SCHED0();
    dot8(acc0, xv0, aC);
    dot8(acc1, xv1, aC);
    dot8(acc2, xv2, aC);
    dot8(acc3, xv3, aC);
    if constexpr (NOTLAST) {
        asm volatile("s_waitcnt vmcnt(8)" ::: "memory");   // x(T+1) landed in LDS
        SCHED0();
        SBAR();                                // raw barrier: A(T+1) stays in flight
        SCHED0();
    }
}
}

// ---- pre-pass (fused): block 0 = wid-sort + per-adapter group build;
//      blocks 1..2048 = x fp32->bf16; trailing blocks zero `out` ----
__global__ __launch_bounds__(256)
void prep(const float* __restrict__ x, uint16_t* __restrict__ xb,
          const int* __restrict__ wids, int* __restrict__ hdr,
          int* __restrict__ grp, float* __restrict__ out, int out_size)
{
    const int bid = blockIdx.x;
    const int t   = threadIdx.x;
    if (bid == 0) {
        __shared__ int hist[NADAPT];
        __shared__ int offs[NADAPT];
        __shared__ int gbase[NADAPT + 1];
        __shared__ int sperm[CBS];
        if (t < NADAPT) hist[t] = 0;
        __syncthreads();
        for (int c = t; c < CBS; c += 256) atomicAdd(&hist[wids[c]], 1);
        __syncthreads();
        if (t == 0) {
            int run = 0, grun = 0;
            for (int i = 0; i < NADAPT; ++i) {
                offs[i]  = run;  run  += hist[i];
                gbase[i] = grun; grun += (hist[i] + GRP - 1) / GRP;
            }
            gbase[NADAPT] = grun;
            hdr[0] = grun;                 // ng
        }
        __syncthreads();
        for (int c = t; c < CBS; c += 256) {
            const int pos = atomicAdd(&offs[wids[c]], 1);
            sperm[pos] = c;
        }
        __syncthreads();
        for (int w = t; w < NADAPT; w += 256) {   // emit uniform groups (pad -1)
            const int cnt   = hist[w];
            const int start = offs[w] - cnt;
            const int gb    = gbase[w];
            for (int i = 0; i < cnt; i += GRP) {
                const int gi = gb + i / GRP;
#pragma unroll
                for (int j = 0; j < GRP; ++j)
                    grp[GRP * gi + j] = (i + j < cnt) ? sperm[start + i + j] : -1;
            }
        }
    } else if (bid <= BATCH * K / 1024) {          // 2048 cvt blocks
        const int i = (bid - 1) * 256 + t;
        const float4 v = ((const float4*)x)[i];
        ushort4 o;
        o.x = f2bf(v.x); o.y = f2bf(v.y); o.z = f2bf(v.z); o.w = f2bf(v.w);
        ((ushort4*)xb)[i] = o;
    } else {                                       // zero out[]
        const int i4 = (bid - (1 + BATCH * K / 1024)) * 256 + t;
        const int e  = i4 * 4;
        if (e + 3 < out_size) {
            ((float4*)out)[i4] = make_float4(0.f, 0.f, 0.f, 0.f);
        } else {
            for (int q = e; q < out_size; ++q) out[q] = 0.f;
        }
    }
}

// ---- main: block (g, s) = one wid-uniform group (<=4 combos) x 512-k slice.
// x staged via global_load_lds (no staging VGPRs, no ds_writes, no spills):
// per instr, 4 consecutive lanes fetch the 4 swizzled 16B quads of one
// 64B-aligned token-row chunk -> 16 line-probes per instr (probe floor).
// A prefetched 1 tile deep into named ping-pong regs, shared across the 4
// combos. Counted vmcnt (12/8) with raw barriers; lane-local k-reduction.
__global__ __launch_bounds__(NT, 4)
void lora_main(const int* __restrict__ xids,
               const int* __restrict__ wids,
               const float* __restrict__ A,
               const uint16_t* __restrict__ xb,
               const int* __restrict__ hdr,
               const int* __restrict__ grp,
               float* __restrict__ out)
{
    __shared__ __align__(16) uint4 xs[2][1024];   // 2 x 16 KiB (double-buffered)
    __shared__ float red[4 * GRP * 64];           // 4 KiB

    const int bid = blockIdx.x;
    const int g   = bid >> 3;
    const int s   = bid & 7;
    if (g >= hdr[0]) return;                // inactive tail blocks

    const int t  = threadIdx.x;
    const int wv = t >> 6;
    const int r  = t & 63;

    const int* gp = grp + GRP * g;
    const int gc0 = gp[0], gc1 = gp[1], gc2 = gp[2], gc3 = gp[3];
    const int myc_raw = (wv == 0) ? gc0 : (wv == 1) ? gc1 : (wv == 2) ? gc2 : gc3;
    const int myc = (myc_raw >= 0) ? myc_raw : gc0;   // pad slots stage dup x
    const int wid = wids[gc0];                        // group is wid-uniform

    // gather-DMA source: lane l covers (row = 16*i + (l>>2), quad = jq) where
    // jq = (l&3) ^ ((l>>3)&3) implements physical slot = row*4 + (quad ^
    // ((row>>1)&3)) under the linear lane*16 DMA dest.
    const int jq = (r & 3) ^ ((r >> 3) & 3);
    const char* __restrict__ xbase =
        (const char*)xb + (size_t)s * KS * 2 + jq * 16;
    uint32_t tokoff[4];
#pragma unroll
    for (int i = 0; i < 4; ++i)
        tokoff[i] = (uint32_t)xids[myc * R + 16 * i + (r >> 2)] * (K * 2);

    // read slot: combo c at +c*256; row r, quad wv -> r*4 + (wv ^ ((r>>1)&3))
    const int rdi = r * 4 + (wv ^ ((r >> 1) & 3));

    const float* __restrict__ Ab =
        A + (size_t)wid * (K * R) + (size_t)(s * KS) * R + r;

    float acc0 = 0.f, acc1 = 0.f, acc2 = 0.f, acc3 = 0.f;
    float aA[8], aB[8];
    uint4* xsb = &xs[0][0];

    // ---- prologue: DMA x(0) -> buf0; A(0) -> aA ----
    {
        uint4* ldst = xsb + wv * 256;
#pragma unroll
        for (int i = 0; i < 4; ++i)
            gload_lds16(xbase + tokoff[i], (void*)(ldst + i * 64));
#pragma unroll
        for (int q = 0; q < 8; ++q) aA[q] = Ab[(size_t)(wv * 8 + q) * R];
        asm volatile("s_waitcnt vmcnt(8)" ::: "memory");   // x(0) landed
        SCHED0();
        SBAR();
        SCHED0();
    }
    // entering tile 0: outstanding = A(0):8

    body< 0, true >(xsb, xbase, tokoff, Ab, wv, rdi, aB, aA, acc0, acc1, acc2, acc3);
    body< 1, true >(xsb, xbase, tokoff, Ab, wv, rdi, aA, aB, acc0, acc1, acc2, acc3);
    body< 2, true >(xsb, xbase, tokoff, Ab, wv, rdi, aB, aA, acc0, acc1, acc2, acc3);
    body< 3, true >(xsb, xbase, tokoff, Ab, wv, rdi, aA, aB, acc0, acc1, acc2, acc3);
    body< 4, true >(xsb, xbase, tokoff, Ab, wv, rdi, aB, aA, acc0, acc1, acc2, acc3);
    body< 5, true >(xsb, xbase, tokoff, Ab, wv, rdi, aA, aB, acc0, acc1, acc2, acc3);
    body< 6, true >(xsb, xbase, tokoff, Ab, wv, rdi, aB, aA, acc0, acc1, acc2, acc3);
    body< 7, true >(xsb, xbase, tokoff, Ab, wv, rdi, aA, aB, acc0, acc1, acc2, acc3);
    body< 8, true >(xsb, xbase, tokoff, Ab, wv, rdi, aB, aA, acc0, acc1, acc2, acc3);
    body< 9, true >(xsb, xbase, tokoff, Ab, wv, rdi, aA, aB, acc0, acc1, acc2, acc3);
    body<10, true >(xsb, xbase, tokoff, Ab, wv, rdi, aB, aA, acc0, acc1, acc2, acc3);
    body<11, true >(xsb, xbase, tokoff, Ab, wv, rdi, aA, aB, acc0, acc1, acc2, acc3);
    body<12, true >(xsb, xbase, tokoff, Ab, wv, rdi, aB, aA, acc0, acc1, acc2, acc3);
    body<13, true >(xsb, xbase, tokoff, Ab, wv, rdi, aA, aB, acc0, acc1, acc2, acc3);
    body<14, true >(xsb, xbase, tokoff, Ab, wv, rdi, aB, aA, acc0, acc1, acc2, acc3);
    body<15, false>(xsb, xbase, tokoff, Ab, wv, rdi, aA, aB, acc0, acc1, acc2, acc3);

    // ---- cross-wave reduce: red[srcwave][slot][r]; wave wv finalizes slot wv ----
    red[wv * 256 +   0 + r] = acc0;
    red[wv * 256 +  64 + r] = acc1;
    red[wv * 256 + 128 + r] = acc2;
    red[wv * 256 + 192 + r] = acc3;
    __syncthreads();
    const float sum = red[0 * 256 + wv * 64 + r] + red[1 * 256 + wv * 64 + r] +
                      red[2 * 256 + wv * 64 + r] + red[3 * 256 + wv * 64 + r];
    if (myc_raw >= 0)
        atomicAdd(&out[myc_raw * R + r], sum);
}

// ---- fallback (ws too small): fp32 x from global, LDS transpose, no perm ----
__global__ __launch_bounds__(NT)
void lora_fallback(const float* __restrict__ x,
                   const int*   __restrict__ xids,
                   const int*   __restrict__ wids,
                   const float* __restrict__ A,
                   float*       __restrict__ out)
{
    constexpr int FKS = 512, FTK = 64, FNT_TILES = 8, FNW = 4;
    __shared__ float xsf[FTK * R];
    __shared__ float red[FNW * R];
    const int bid  = blockIdx.x;
    const int c    = bid >> 3;
    const int s    = bid & 7;
    const int t    = threadIdx.x;
    const int wave = t >> 6;
    const int lane = t & 63;
    const int r4   = lane & 15;
    const int kq   = lane >> 4;
    const int wid  = wids[c];
    const float* __restrict__ Aw = A + (size_t)wid * (K * R);
    const int rw  = t >> 2;
    const int jq  = t & 3;
    const int tok = xids[c * R + rw];
    const float* __restrict__ xrow = x + (size_t)tok * K + s * FKS + jq * 16;
    float4 acc = make_float4(0.f, 0.f, 0.f, 0.f);
    float4 pv[4];
    {
        const float4* src = (const float4*)xrow;
#pragma unroll
        for (int ii = 0; ii < 4; ++ii) pv[ii] = src[ii];
    }
    for (int tile = 0; tile < FNT_TILES; ++tile) {
#pragma unroll
        for (int ii = 0; ii < 4; ++ii) {
            const int kk = jq * 16 + ii * 4;
            xsf[(kk + 0) * R + rw] = pv[ii].x;
            xsf[(kk + 1) * R + rw] = pv[ii].y;
            xsf[(kk + 2) * R + rw] = pv[ii].z;
            xsf[(kk + 3) * R + rw] = pv[ii].w;
        }
        __syncthreads();
        if (tile + 1 < FNT_TILES) {
            const float4* src = (const float4*)(xrow + (tile + 1) * FTK);
#pragma unroll
            for (int ii = 0; ii < 4; ++ii) pv[ii] = src[ii];
        }
        const int kw = wave * 16 + kq;
        const float* __restrict__ Ap =
            Aw + (size_t)(s * FKS + tile * FTK + kw) * R + 4 * r4;
#pragma unroll
        for (int i = 0; i < 4; ++i) {
            float4 av = *(const float4*)(Ap + (size_t)(4 * i) * R);
            float4 xv = *(const float4*)(&xsf[(kw + 4 * i) * R + 4 * r4]);
            acc.x = fmaf(xv.x, av.x, acc.x);
            acc.y = fmaf(xv.y, av.y, acc.y);
            acc.z = fmaf(xv.z, av.z, acc.z);
            acc.w = fmaf(xv.w, av.w, acc.w);
        }
        __syncthreads();
    }
#pragma unroll
    for (int m = 16; m < 64; m <<= 1) {
        acc.x += __shfl_xor(acc.x, m, 64);
        acc.y += __shfl_xor(acc.y, m, 64);
        acc.z += __shfl_xor(acc.z, m, 64);
        acc.w += __shfl_xor(acc.w, m, 64);
    }
    if (kq == 0) {
        float* rd = &red[wave * R + 4 * r4];
        rd[0] = acc.x; rd[1] = acc.y; rd[2] = acc.z; rd[3] = acc.w;
    }
    __syncthreads();
    if (wave == 0) {
        float sum = red[lane] + red[R + lane] + red[2 * R + lane] + red[3 * R + lane];
        atomicAdd(&out[c * R + lane], sum);
    }
}

extern "C" void kernel_launch(void* const* d_in, const int* in_sizes, int n_in,
                              void* d_out, int out_size, void* d_ws, size_t ws_size,
                              hipStream_t stream)
{
    (void)in_sizes; (void)n_in;
    const float* x    = (const float*)d_in[0];
    const int*   xids = (const int*)d_in[1];
    const int*   wids = (const int*)d_in[2];
    const float* A    = (const float*)d_in[3];
    float* out        = (float*)d_out;

    if (ws_size >= WS_NEEDED) {
        int*      hdr = (int*)d_ws;
        int*      grp = (int*)((char*)d_ws + WS_GRP_OFF);
        uint16_t* xbw = (uint16_t*)((char*)d_ws + WS_X_OFF);
        const int ncvt = BATCH * K / 1024;              // 2048
        const int nz   = (out_size + 1023) / 1024;      // out-zero blocks
        hipLaunchKernelGGL(prep, dim3(1 + ncvt + nz), dim3(256), 0, stream,
                           x, xbw, wids, hdr, grp, out, out_size);
        hipLaunchKernelGGL(lora_main, dim3(NGMAX * SPLIT), dim3(NT), 0, stream,
                           xids, wids, A, xbw, hdr, grp, out);
    } else {
        hipMemsetAsync(out, 0, (size_t)out_size * sizeof(float), stream);
        hipLaunchKernelGGL(lora_fallback, dim3(CBS * 8), dim3(NT), 0, stream,
                           x, xids, wids, A, out);
    }
}

// Round 7
// 147.287 us; speedup vs baseline: 1.5279x; 1.0276x over previous
//
#include <hip/hip_runtime.h>
#include <stdint.h>

namespace {
constexpr int BATCH  = 512;
constexpr int CBS    = 320;       // combined batch size
constexpr int R      = 64;        // rank
constexpr int K      = 4096;
constexpr int NADAPT = 80;
constexpr int GRP    = 4;         // combos per block (always wid-uniform)
constexpr int NGMAX  = 140;       // max groups: sum ceil(cnt/4) <= (320+3*80)/4
constexpr int SPLIT  = 16;        // k-slices -> 2240 blocks (~1760 active, ~7/CU)
constexpr int KS     = K / SPLIT; // 256 k per block
constexpr int TK     = 32;        // k per LDS tile (64 B per row)
constexpr int NTILE  = KS / TK;   // 8
constexpr int NT     = 256;       // 4 waves

// ws layout: hdr[16] ints at 0 (hdr[0]=ng); grp[NGMAX*4] ints at byte 64;
// x_bf16[512][4096] at byte 4096
constexpr size_t WS_GRP_OFF = 64;
constexpr size_t WS_X_OFF   = 4096;
constexpr size_t WS_NEEDED  = WS_X_OFF + (size_t)BATCH * K * 2;  // ~4.2 MiB

__device__ inline uint16_t f2bf(float f) {   // RNE fp32 -> bf16
    uint32_t u = __float_as_uint(f);
    u += 0x7fffu + ((u >> 16) & 1u);
    return (uint16_t)(u >> 16);
}
__device__ inline float bflo(uint32_t u) { return __uint_as_float(u << 16); }
__device__ inline float bfhi(uint32_t u) { return __uint_as_float(u & 0xffff0000u); }

__device__ __forceinline__ void dot8(float& acc, const uint4 v, const float (&a)[8]) {
    acc = fmaf(bflo(v.x), a[0], acc);
    acc = fmaf(bfhi(v.x), a[1], acc);
    acc = fmaf(bflo(v.y), a[2], acc);
    acc = fmaf(bfhi(v.y), a[3], acc);
    acc = fmaf(bflo(v.z), a[4], acc);
    acc = fmaf(bfhi(v.z), a[5], acc);
    acc = fmaf(bflo(v.w), a[6], acc);
    acc = fmaf(bfhi(v.w), a[7], acc);
}

#define WAITL() asm volatile("s_waitcnt lgkmcnt(0)" ::: "memory")
#define SCHED0() __builtin_amdgcn_sched_barrier(0)
#define SBAR()  __builtin_amdgcn_s_barrier()

// DMA 16 B/lane global->LDS. LDS dest = wave-uniform base + lane*16 (linear);
// the swizzle lives in the per-lane GLOBAL address (rule #21).
__device__ __forceinline__ void gload_lds16(const void* g, void* l) {
    __builtin_amdgcn_global_load_lds(
        (const __attribute__((address_space(1))) void*)g,
        (__attribute__((address_space(3))) void*)l, 16, 0, 0);
}

// Single-buffer 2-barrier tile. Invariant entering tile T: outstanding = A(T):8.
//   ds_read(T) -> lgkm(0) -> SBAR          (buffer free: reads are in regs)
//   issue x(T+1) DMA:4 + A(T+1):8          (-> 20 outstanding)
//   vmcnt(12): A(T) landed -> FMAs
//   vmcnt(8):  x(T+1) in LDS -> SBAR       (A(T+1) stays in flight)
template<int T, bool NOTLAST>
__device__ __forceinline__ void body(
    uint4* __restrict__ xsb,                  // &xs[0] : [1024] 16B slots
    const char* __restrict__ xbase,           // xb + s*KS*2 + jq*16 (lane-swizzled)
    const uint32_t (&tokoff)[4],              // per-instr token-row byte offsets
    const float* __restrict__ Ab,
    int wv, int rdi,
    float (&aN)[8], const float (&aC)[8],
    float& acc0, float& acc1, float& acc2, float& acc3)
{
    const uint4* Bp = xsb + rdi;
    const uint4 xv0 = Bp[0];
    const uint4 xv1 = Bp[256];
    const uint4 xv2 = Bp[512];
    const uint4 xv3 = Bp[768];
    WAITL();                                   // x(T) values now in registers
    SCHED0();
    SBAR();                                    // all waves done reading buffer
    SCHED0();
    if constexpr (NOTLAST) {
        uint4* ldst = xsb + wv * 256;          // overwrite combo-wv section
#pragma unroll
        for (int i = 0; i < 4; ++i)
            gload_lds16(xbase + tokoff[i] + (size_t)(T + 1) * 64,
                        (void*)(ldst + i * 64));
#pragma unroll
        for (int q = 0; q < 8; ++q)
            aN[q] = Ab[((size_t)((T + 1) * TK) + wv * 8 + q) * R];
        asm volatile("s_waitcnt vmcnt(12)" ::: "memory");  // A(T) landed
    } else {
        asm volatile("s_waitcnt vmcnt(0)" ::: "memory");   // epilogue drain
    }
    SCHED0();
    dot8(acc0, xv0, aC);
    dot8(acc1, xv1, aC);
    dot8(acc2, xv2, aC);
    dot8(acc3, xv3, aC);
    if constexpr (NOTLAST) {
        asm volatile("s_waitcnt vmcnt(8)" ::: "memory");   // x(T+1) landed in LDS
        SCHED0();
        SBAR();                                // A(T+1) stays in flight
        SCHED0();
    }
}
}

// ---- pre-pass (fused): block 0 = wid-sort + per-adapter group build;
//      blocks 1..2048 = x fp32->bf16; trailing blocks zero `out` ----
__global__ __launch_bounds__(256)
void prep(const float* __restrict__ x, uint16_t* __restrict__ xb,
          const int* __restrict__ wids, int* __restrict__ hdr,
          int* __restrict__ grp, float* __restrict__ out, int out_size)
{
    const int bid = blockIdx.x;
    const int t   = threadIdx.x;
    if (bid == 0) {
        __shared__ int hist[NADAPT];
        __shared__ int offs[NADAPT];
        __shared__ int gbase[NADAPT + 1];
        __shared__ int sperm[CBS];
        if (t < NADAPT) hist[t] = 0;
        __syncthreads();
        for (int c = t; c < CBS; c += 256) atomicAdd(&hist[wids[c]], 1);
        __syncthreads();
        if (t == 0) {
            int run = 0, grun = 0;
            for (int i = 0; i < NADAPT; ++i) {
                offs[i]  = run;  run  += hist[i];
                gbase[i] = grun; grun += (hist[i] + GRP - 1) / GRP;
            }
            gbase[NADAPT] = grun;
            hdr[0] = grun;                 // ng
        }
        __syncthreads();
        for (int c = t; c < CBS; c += 256) {
            const int pos = atomicAdd(&offs[wids[c]], 1);
            sperm[pos] = c;
        }
        __syncthreads();
        for (int w = t; w < NADAPT; w += 256) {   // emit uniform groups (pad -1)
            const int cnt   = hist[w];
            const int start = offs[w] - cnt;
            const int gb    = gbase[w];
            for (int i = 0; i < cnt; i += GRP) {
                const int gi = gb + i / GRP;
#pragma unroll
                for (int j = 0; j < GRP; ++j)
                    grp[GRP * gi + j] = (i + j < cnt) ? sperm[start + i + j] : -1;
            }
        }
    } else if (bid <= BATCH * K / 1024) {          // 2048 cvt blocks
        const int i = (bid - 1) * 256 + t;
        const float4 v = ((const float4*)x)[i];
        ushort4 o;
        o.x = f2bf(v.x); o.y = f2bf(v.y); o.z = f2bf(v.z); o.w = f2bf(v.w);
        ((ushort4*)xb)[i] = o;
    } else {                                       // zero out[]
        const int i4 = (bid - (1 + BATCH * K / 1024)) * 256 + t;
        const int e  = i4 * 4;
        if (e + 3 < out_size) {
            ((float4*)out)[i4] = make_float4(0.f, 0.f, 0.f, 0.f);
        } else {
            for (int q = e; q < out_size; ++q) out[q] = 0.f;
        }
    }
}

// ---- main: block (g, s) = one wid-uniform group (<=4 combos) x 256-k slice.
// 20 KB LDS (single x-buffer + red) -> 8 blocks/CU; grid ~1760 active blocks
// (~7/CU) so A-latency is covered by TLP (8 waves/SIMD). x staged via
// global_load_lds gathers at the probe floor (16 line-probes/instr); A
// prefetched 1 tile into named ping-pong regs, shared across the 4 combos.
__global__ __launch_bounds__(NT, 8)
void lora_main(const int* __restrict__ xids,
               const int* __restrict__ wids,
               const float* __restrict__ A,
               const uint16_t* __restrict__ xb,
               const int* __restrict__ hdr,
               const int* __restrict__ grp,
               float* __restrict__ out)
{
    __shared__ __align__(16) uint4 xs[1024];      // 16 KiB (single-buffered)
    __shared__ float red[4 * GRP * 64];           // 4 KiB

    const int bid = blockIdx.x;
    const int g   = bid >> 4;
    const int s   = bid & 15;
    if (g >= hdr[0]) return;                // inactive tail blocks (uniform exit)

    const int t  = threadIdx.x;
    const int wv = t >> 6;
    const int r  = t & 63;

    const int* gp = grp + GRP * g;
    const int gc0 = gp[0], gc1 = gp[1], gc2 = gp[2], gc3 = gp[3];
    const int myc_raw = (wv == 0) ? gc0 : (wv == 1) ? gc1 : (wv == 2) ? gc2 : gc3;
    const int myc = (myc_raw >= 0) ? myc_raw : gc0;   // pad slots stage dup x
    const int wid = wids[gc0];                        // group is wid-uniform

    // gather-DMA source: lane l covers (row = 16*i + (l>>2), quad = jq) where
    // jq = (l&3) ^ ((l>>3)&3) implements physical slot = row*4 + (quad ^
    // ((row>>1)&3)) under the linear lane*16 DMA dest.
    const int jq = (r & 3) ^ ((r >> 3) & 3);
    const char* __restrict__ xbase =
        (const char*)xb + (size_t)s * KS * 2 + jq * 16;
    uint32_t tokoff[4];
#pragma unroll
    for (int i = 0; i < 4; ++i)
        tokoff[i] = (uint32_t)xids[myc * R + 16 * i + (r >> 2)] * (K * 2);

    // read slot: combo c at +c*256; row r, quad wv -> r*4 + (wv ^ ((r>>1)&3))
    const int rdi = r * 4 + (wv ^ ((r >> 1) & 3));

    const float* __restrict__ Ab =
        A + (size_t)wid * (K * R) + (size_t)(s * KS) * R + r;

    float acc0 = 0.f, acc1 = 0.f, acc2 = 0.f, acc3 = 0.f;
    float aA[8], aB[8];
    uint4* xsb = &xs[0];

    // ---- prologue: DMA x(0) -> buffer; A(0) -> aA ----
    {
        uint4* ldst = xsb + wv * 256;
#pragma unroll
        for (int i = 0; i < 4; ++i)
            gload_lds16(xbase + tokoff[i], (void*)(ldst + i * 64));
#pragma unroll
        for (int q = 0; q < 8; ++q) aA[q] = Ab[(size_t)(wv * 8 + q) * R];
        asm volatile("s_waitcnt vmcnt(8)" ::: "memory");   // x(0) landed
        SCHED0();
        SBAR();
        SCHED0();
    }
    // entering tile 0: outstanding = A(0):8

    body<0, true >(xsb, xbase, tokoff, Ab, wv, rdi, aB, aA, acc0, acc1, acc2, acc3);
    body<1, true >(xsb, xbase, tokoff, Ab, wv, rdi, aA, aB, acc0, acc1, acc2, acc3);
    body<2, true >(xsb, xbase, tokoff, Ab, wv, rdi, aB, aA, acc0, acc1, acc2, acc3);
    body<3, true >(xsb, xbase, tokoff, Ab, wv, rdi, aA, aB, acc0, acc1, acc2, acc3);
    body<4, true >(xsb, xbase, tokoff, Ab, wv, rdi, aB, aA, acc0, acc1, acc2, acc3);
    body<5, true >(xsb, xbase, tokoff, Ab, wv, rdi, aA, aB, acc0, acc1, acc2, acc3);
    body<6, true >(xsb, xbase, tokoff, Ab, wv, rdi, aB, aA, acc0, acc1, acc2, acc3);
    body<7, false>(xsb, xbase, tokoff, Ab, wv, rdi, aA, aB, acc0, acc1, acc2, acc3);

    // ---- cross-wave reduce: red[srcwave][slot][r]; wave wv finalizes slot wv ----
    red[wv * 256 +   0 + r] = acc0;
    red[wv * 256 +  64 + r] = acc1;
    red[wv * 256 + 128 + r] = acc2;
    red[wv * 256 + 192 + r] = acc3;
    __syncthreads();
    const float sum = red[0 * 256 + wv * 64 + r] + red[1 * 256 + wv * 64 + r] +
                      red[2 * 256 + wv * 64 + r] + red[3 * 256 + wv * 64 + r];
    if (myc_raw >= 0)
        atomicAdd(&out[myc_raw * R + r], sum);
}

// ---- fallback (ws too small): fp32 x from global, LDS transpose, no perm ----
__global__ __launch_bounds__(NT)
void lora_fallback(const float* __restrict__ x,
                   const int*   __restrict__ xids,
                   const int*   __restrict__ wids,
                   const float* __restrict__ A,
                   float*       __restrict__ out)
{
    constexpr int FKS = 512, FTK = 64, FNT_TILES = 8, FNW = 4;
    __shared__ float xsf[FTK * R];
    __shared__ float red[FNW * R];
    const int bid  = blockIdx.x;
    const int c    = bid >> 3;
    const int s    = bid & 7;
    const int t    = threadIdx.x;
    const int wave = t >> 6;
    const int lane = t & 63;
    const int r4   = lane & 15;
    const int kq   = lane >> 4;
    const int wid  = wids[c];
    const float* __restrict__ Aw = A + (size_t)wid * (K * R);
    const int rw  = t >> 2;
    const int jq  = t & 3;
    const int tok = xids[c * R + rw];
    const float* __restrict__ xrow = x + (size_t)tok * K + s * FKS + jq * 16;
    float4 acc = make_float4(0.f, 0.f, 0.f, 0.f);
    float4 pv[4];
    {
        const float4* src = (const float4*)xrow;
#pragma unroll
        for (int ii = 0; ii < 4; ++ii) pv[ii] = src[ii];
    }
    for (int tile = 0; tile < FNT_TILES; ++tile) {
#pragma unroll
        for (int ii = 0; ii < 4; ++ii) {
            const int kk = jq * 16 + ii * 4;
            xsf[(kk + 0) * R + rw] = pv[ii].x;
            xsf[(kk + 1) * R + rw] = pv[ii].y;
            xsf[(kk + 2) * R + rw] = pv[ii].z;
            xsf[(kk + 3) * R + rw] = pv[ii].w;
        }
        __syncthreads();
        if (tile + 1 < FNT_TILES) {
            const float4* src = (const float4*)(xrow + (tile + 1) * FTK);
#pragma unroll
            for (int ii = 0; ii < 4; ++ii) pv[ii] = src[ii];
        }
        const int kw = wave * 16 + kq;
        const float* __restrict__ Ap =
            Aw + (size_t)(s * FKS + tile * FTK + kw) * R + 4 * r4;
#pragma unroll
        for (int i = 0; i < 4; ++i) {
            float4 av = *(const float4*)(Ap + (size_t)(4 * i) * R);
            float4 xv = *(const float4*)(&xsf[(kw + 4 * i) * R + 4 * r4]);
            acc.x = fmaf(xv.x, av.x, acc.x);
            acc.y = fmaf(xv.y, av.y, acc.y);
            acc.z = fmaf(xv.z, av.z, acc.z);
            acc.w = fmaf(xv.w, av.w, acc.w);
        }
        __syncthreads();
    }
#pragma unroll
    for (int m = 16; m < 64; m <<= 1) {
        acc.x += __shfl_xor(acc.x, m, 64);
        acc.y += __shfl_xor(acc.y, m, 64);
        acc.z += __shfl_xor(acc.z, m, 64);
        acc.w += __shfl_xor(acc.w, m, 64);
    }
    if (kq == 0) {
        float* rd = &red[wave * R + 4 * r4];
        rd[0] = acc.x; rd[1] = acc.y; rd[2] = acc.z; rd[3] = acc.w;
    }
    __syncthreads();
    if (wave == 0) {
        float sum = red[lane] + red[R + lane] + red[2 * R + lane] + red[3 * R + lane];
        atomicAdd(&out[c * R + lane], sum);
    }
}

extern "C" void kernel_launch(void* const* d_in, const int* in_sizes, int n_in,
                              void* d_out, int out_size, void* d_ws, size_t ws_size,
                              hipStream_t stream)
{
    (void)in_sizes; (void)n_in;
    const float* x    = (const float*)d_in[0];
    const int*   xids = (const int*)d_in[1];
    const int*   wids = (const int*)d_in[2];
    const float* A    = (const float*)d_in[3];
    float* out        = (float*)d_out;

    if (ws_size >= WS_NEEDED) {
        int*      hdr = (int*)d_ws;
        int*      grp = (int*)((char*)d_ws + WS_GRP_OFF);
        uint16_t* xbw = (uint16_t*)((char*)d_ws + WS_X_OFF);
        const int ncvt = BATCH * K / 1024;              // 2048
        const int nz   = (out_size + 1023) / 1024;      // out-zero blocks
        hipLaunchKernelGGL(prep, dim3(1 + ncvt + nz), dim3(256), 0, stream,
                           x, xbw, wids, hdr, grp, out, out_size);
        hipLaunchKernelGGL(lora_main, dim3(NGMAX * SPLIT), dim3(NT), 0, stream,
                           xids, wids, A, xbw, hdr, grp, out);
    } else {
        hipMemsetAsync(out, 0, (size_t)out_size * sizeof(float), stream);
        hipLaunchKernelGGL(lora_fallback, dim3(CBS * 8), dim3(NT), 0, stream,
                           x, xids, wids, A, out);
    }
}